// Round 1
// baseline (23273.546 us; speedup 1.0000x reference)
//
#include <hip/hip_runtime.h>
#include <math.h>

#define NN 100000
#define EE 1600000
#define FF 128
#define CC 256

// ---------------------------------------------------------------------------
// Unified fp32 GEMM:
//   C[m, 0:256] = (K1>0 ? (A1[m,:]*invc[m]) @ B1 : 0) + A2[m,:] @ B2
//                 (+ bias1)(+ bias2)(optional sigmoid)
// BM=64, BN=256 (full output width per block -> in-place C=A2 update is safe),
// BK=16, 256 threads, 8x8 microtile per thread (split 4+4 rows / 4+4 cols to
// keep LDS reads on contiguous float4 chunks).
// ---------------------------------------------------------------------------
template<int K1, int K2, bool SIG>
__global__ __launch_bounds__(256)
void gemm_kernel(const float* __restrict__ A1, const float* __restrict__ invc,
                 const float* __restrict__ A2,
                 const float* __restrict__ B1, const float* __restrict__ B2,
                 const float* __restrict__ bias1, const float* __restrict__ bias2,
                 float* __restrict__ Cout, int M)
{
    constexpr int BM = 64, BK = 16;
    __shared__ float As[BK][BM + 4];    // stride 68 floats = 272B (16B-aligned rows)
    __shared__ float Bs[BK][CC + 4];    // stride 260 floats = 1040B (16B-aligned rows)

    const int tid = threadIdx.x;
    const int tx = tid & 31;            // 0..31 -> cols tx*4 and 128+tx*4
    const int ty = tid >> 5;            // 0..7  -> rows ty*4 and 32+ty*4
    const int m0 = blockIdx.x * BM;

    // A staging map: each thread loads one float4: row tid/4, k-offset (tid&3)*4
    const int lrow = tid >> 2;          // 0..63
    const int lk   = (tid & 3) << 2;    // 0,4,8,12
    int grow = m0 + lrow;
    if (grow > M - 1) grow = M - 1;     // clamp; stores are predicated

    float sA = 1.0f;
    if (K1 > 0) sA = invc[grow];        // per-row mean divisor for the agg segment

    float acc[8][8];
#pragma unroll
    for (int i = 0; i < 8; i++)
#pragma unroll
        for (int j = 0; j < 8; j++) acc[i][j] = 0.0f;

    for (int k0 = 0; k0 < K1 + K2; k0 += BK) {
        const float* Ap; const float* Bp; int kk0; float sc; int lda;
        if (K1 > 0 && k0 < K1) { Ap = A1; Bp = B1; kk0 = k0;      sc = sA;   lda = CC; }
        else                   { Ap = A2; Bp = B2; kk0 = k0 - K1; sc = 1.0f; lda = K2; }

        // stage A tile (transposed into LDS, scaled)
        {
            const float4 av = *(const float4*)(Ap + (size_t)grow * lda + (kk0 + lk));
            As[lk + 0][lrow] = av.x * sc;
            As[lk + 1][lrow] = av.y * sc;
            As[lk + 2][lrow] = av.z * sc;
            As[lk + 3][lrow] = av.w * sc;
        }
        // stage B tile: 16 rows x 256 cols, 4 passes of (4 rows x 64 float4s)
#pragma unroll
        for (int p = 0; p < 4; p++) {
            const int bk = (tid >> 6) + (p << 2);    // 0..15
            const int bc = (tid & 63) << 2;          // 0..252
            *(float4*)&Bs[bk][bc] = *(const float4*)(Bp + (size_t)(kk0 + bk) * CC + bc);
        }
        __syncthreads();

#pragma unroll
        for (int kk = 0; kk < BK; kk++) {
            float a[8], b[8];
            *(float4*)&a[0] = *(const float4*)&As[kk][(ty << 2)];
            *(float4*)&a[4] = *(const float4*)&As[kk][32 + (ty << 2)];
            *(float4*)&b[0] = *(const float4*)&Bs[kk][(tx << 2)];
            *(float4*)&b[4] = *(const float4*)&Bs[kk][128 + (tx << 2)];
#pragma unroll
            for (int i = 0; i < 8; i++)
#pragma unroll
                for (int j = 0; j < 8; j++)
                    acc[i][j] = fmaf(a[i], b[j], acc[i][j]);
        }
        __syncthreads();
    }

    // epilogue: biases (+ optional sigmoid), predicated float4 stores
    float badd[8];
    {
        float4 a1 = make_float4(0.f, 0.f, 0.f, 0.f), a2 = make_float4(0.f, 0.f, 0.f, 0.f);
        if (bias1) {
            a1 = *(const float4*)(bias1 + (tx << 2));
            a2 = *(const float4*)(bias1 + 128 + (tx << 2));
        }
        if (bias2) {
            const float4 c1 = *(const float4*)(bias2 + (tx << 2));
            const float4 c2 = *(const float4*)(bias2 + 128 + (tx << 2));
            a1.x += c1.x; a1.y += c1.y; a1.z += c1.z; a1.w += c1.w;
            a2.x += c2.x; a2.y += c2.y; a2.z += c2.z; a2.w += c2.w;
        }
        badd[0] = a1.x; badd[1] = a1.y; badd[2] = a1.z; badd[3] = a1.w;
        badd[4] = a2.x; badd[5] = a2.y; badd[6] = a2.z; badd[7] = a2.w;
    }

#pragma unroll
    for (int i = 0; i < 8; i++) {
        const int rf = (i < 4) ? ((ty << 2) + i) : (32 + (ty << 2) + i - 4);
        const int row = m0 + rf;
        if (row < M) {
            float v[8];
#pragma unroll
            for (int j = 0; j < 8; j++) {
                float t = acc[i][j] + badd[j];
                if (SIG) t = 1.0f / (1.0f + __expf(-t));
                v[j] = t;
            }
            *(float4*)(Cout + (size_t)row * CC + (tx << 2))       = make_float4(v[0], v[1], v[2], v[3]);
            *(float4*)(Cout + (size_t)row * CC + 128 + (tx << 2)) = make_float4(v[4], v[5], v[6], v[7]);
        }
    }
}

// ---------------------------------------------------------------------------
// Edge scatter-add: one wave (64 lanes) per edge, each lane handles 4 channels.
// Gather is a coalesced 1KB row read; scatter is 4 fp32 atomics per lane.
// ---------------------------------------------------------------------------
__global__ __launch_bounds__(256)
void scatter_kernel(const float* __restrict__ feat, const int* __restrict__ src,
                    const int* __restrict__ dst, float* __restrict__ agg)
{
    const long long gid = (long long)blockIdx.x * 256 + threadIdx.x;
    const int e = (int)(gid >> 6);
    if (e >= EE) return;
    const int lane = (int)(gid & 63);
    const int s = src[e];
    const int d = dst[e];
    const float4 v = *(const float4*)(feat + (size_t)s * CC + (lane << 2));
    float* p = agg + (size_t)d * CC + (lane << 2);
    atomicAdd(p + 0, v.x);
    atomicAdd(p + 1, v.y);
    atomicAdd(p + 2, v.z);
    atomicAdd(p + 3, v.w);
}

__global__ __launch_bounds__(256)
void count_kernel(const int* __restrict__ dst, float* __restrict__ cnt)
{
    const int g = blockIdx.x * 256 + threadIdx.x;
    if (g < EE) atomicAdd(&cnt[dst[g]], 1.0f);
}

__global__ __launch_bounds__(256)
void inv_kernel(float* __restrict__ c)
{
    const int g = blockIdx.x * 256 + threadIdx.x;
    if (g < NN) c[g] = 1.0f / fmaxf(c[g], 1.0f);
}

// ---------------------------------------------------------------------------
extern "C" void kernel_launch(void* const* d_in, const int* in_sizes, int n_in,
                              void* d_out, int out_size, void* d_ws, size_t ws_size,
                              hipStream_t stream)
{
    const float* x_A    = (const float*)d_in[0];
    const float* x_B    = (const float*)d_in[1];
    // d_in[2], d_in[3] = h_A, h_B: unused by reference
    const int*   e_ab   = (const int*)d_in[4];
    const int*   e_ba   = (const int*)d_in[5];
    const float* lin_A  = (const float*)d_in[6];
    const float* lin_B  = (const float*)d_in[7];
    const float* bias_A = (const float*)d_in[8];
    const float* bias_B = (const float*)d_in[9];
    const float* Wl_ab0 = (const float*)d_in[10]; const float* bl_ab0 = (const float*)d_in[11]; const float* Wr_ab0 = (const float*)d_in[12];
    const float* Wl_ba0 = (const float*)d_in[13]; const float* bl_ba0 = (const float*)d_in[14]; const float* Wr_ba0 = (const float*)d_in[15];
    const float* Wl_ab1 = (const float*)d_in[16]; const float* bl_ab1 = (const float*)d_in[17]; const float* Wr_ab1 = (const float*)d_in[18];
    const float* Wl_ba1 = (const float*)d_in[19]; const float* bl_ba1 = (const float*)d_in[20]; const float* Wr_ba1 = (const float*)d_in[21];

    float* gA = (float*)d_out;                    // [N, C] (layer outputs for A live here)
    float* gB = gA + (size_t)NN * CC;             // [N, C]

    // workspace: bufA | bufB | agg | invA | invB  (= 308 MB)
    float* bufA = (float*)d_ws;
    float* bufB = bufA + (size_t)NN * CC;
    float* agg  = bufB + (size_t)NN * CC;
    float* invA = agg  + (size_t)NN * CC;
    float* invB = invA + NN;

    const int* src_ab = e_ab;  const int* dst_ab = e_ab + EE;
    const int* src_ba = e_ba;  const int* dst_ba = e_ba + EE;

    const int gM   = (NN + 63) / 64;                               // 1563
    const int gE1  = (EE + 255) / 256;
    const int gE64 = (int)(((long long)EE * 64 + 255) / 256);      // 400000
    const int gN   = (NN + 255) / 256;
    const size_t aggBytes = (size_t)NN * CC * sizeof(float);

    // degree counts -> reciprocal of mean divisor (shared by both layers)
    hipMemsetAsync(invA, 0, NN * sizeof(float), stream);
    hipMemsetAsync(invB, 0, NN * sizeof(float), stream);
    count_kernel<<<gE1, 256, 0, stream>>>(dst_ba, invA);
    count_kernel<<<gE1, 256, 0, stream>>>(dst_ab, invB);
    inv_kernel<<<gN, 256, 0, stream>>>(invA);
    inv_kernel<<<gN, 256, 0, stream>>>(invB);

    // input projections: oA = x_A @ lin_A, oB = x_B @ lin_B
    gemm_kernel<0, FF, false><<<gM, 256, 0, stream>>>(nullptr, nullptr, x_A, nullptr, lin_A, nullptr, nullptr, bufA, NN);
    gemm_kernel<0, FF, false><<<gM, 256, 0, stream>>>(nullptr, nullptr, x_B, nullptr, lin_B, nullptr, nullptr, bufB, NN);

    // layer 0, A side: mean_{B->A}(oB) @ Wl_ba0 + bl_ba0 + oA @ Wr_ba0 -> nA (in gA)
    hipMemsetAsync(agg, 0, aggBytes, stream);
    scatter_kernel<<<gE64, 256, 0, stream>>>(bufB, src_ba, dst_ba, agg);
    gemm_kernel<CC, CC, false><<<gM, 256, 0, stream>>>(agg, invA, bufA, Wl_ba0, Wr_ba0, bl_ba0, nullptr, gA, NN);

    // layer 0, B side (agg buffer reused; oA no longer needed after this GEMM)
    hipMemsetAsync(agg, 0, aggBytes, stream);
    scatter_kernel<<<gE64, 256, 0, stream>>>(bufA, src_ab, dst_ab, agg);
    gemm_kernel<CC, CC, false><<<gM, 256, 0, stream>>>(agg, invB, bufB, Wl_ab0, Wr_ab0, bl_ab0, nullptr, gB, NN);

    // layer 1: scatter BOTH aggregations first (nA/nB still intact in d_out),
    // reusing bufA as the second agg buffer (oA is dead now).
    hipMemsetAsync(agg, 0, aggBytes, stream);
    scatter_kernel<<<gE64, 256, 0, stream>>>(gB, src_ba, dst_ba, agg);   // nB messages -> A
    hipMemsetAsync(bufA, 0, aggBytes, stream);
    scatter_kernel<<<gE64, 256, 0, stream>>>(gA, src_ab, dst_ab, bufA);  // nA messages -> B

    // layer 1 GEMMs fused with final per-type bias + sigmoid, in-place into d_out.
    // Safe: each block reads only its own 64 rows of the in-place operand (BN=256).
    gemm_kernel<CC, CC, true><<<gM, 256, 0, stream>>>(agg,  invA, gA, Wl_ba1, Wr_ba1, bl_ba1, bias_A, gA, NN);
    gemm_kernel<CC, CC, true><<<gM, 256, 0, stream>>>(bufA, invB, gB, Wl_ab1, Wr_ab1, bl_ab1, bias_B, gB, NN);
}

// Round 2
// 3190.051 us; speedup vs baseline: 7.2957x; 7.2957x over previous
//
#include <hip/hip_runtime.h>
#include <math.h>

#define NN 100000
#define EE 1600000
#define FF 128
#define CC 256

// ---------------------------------------------------------------------------
// Unified fp32 GEMM:
//   C[m, 0:256] = (K1>0 ? A1[m,:] @ B1 : 0) + A2[m,:] @ B2
//                 (+ bias1)(+ bias2)(optional sigmoid)
// BM=64, BN=256 (full output width per block -> in-place C=A2 update is safe),
// BK=16, 256 threads, 8x8 microtile per thread.
// ---------------------------------------------------------------------------
template<int K1, int K2, bool SIG>
__global__ __launch_bounds__(256)
void gemm_kernel(const float* __restrict__ A1, const float* __restrict__ A2,
                 const float* __restrict__ B1, const float* __restrict__ B2,
                 const float* __restrict__ bias1, const float* __restrict__ bias2,
                 float* __restrict__ Cout, int M)
{
    constexpr int BM = 64, BK = 16;
    __shared__ float As[BK][BM + 4];
    __shared__ float Bs[BK][CC + 4];

    const int tid = threadIdx.x;
    const int tx = tid & 31;            // cols tx*4 and 128+tx*4
    const int ty = tid >> 5;            // rows ty*4 and 32+ty*4
    const int m0 = blockIdx.x * BM;

    const int lrow = tid >> 2;          // 0..63
    const int lk   = (tid & 3) << 2;    // 0,4,8,12
    int grow = m0 + lrow;
    if (grow > M - 1) grow = M - 1;     // clamp; stores are predicated

    float acc[8][8];
#pragma unroll
    for (int i = 0; i < 8; i++)
#pragma unroll
        for (int j = 0; j < 8; j++) acc[i][j] = 0.0f;

    for (int k0 = 0; k0 < K1 + K2; k0 += BK) {
        const float* Ap; const float* Bp; int kk0; int lda;
        if (K1 > 0 && k0 < K1) { Ap = A1; Bp = B1; kk0 = k0;      lda = CC; }
        else                   { Ap = A2; Bp = B2; kk0 = k0 - K1; lda = K2; }

        {
            const float4 av = *(const float4*)(Ap + (size_t)grow * lda + (kk0 + lk));
            As[lk + 0][lrow] = av.x;
            As[lk + 1][lrow] = av.y;
            As[lk + 2][lrow] = av.z;
            As[lk + 3][lrow] = av.w;
        }
#pragma unroll
        for (int p = 0; p < 4; p++) {
            const int bk = (tid >> 6) + (p << 2);
            const int bc = (tid & 63) << 2;
            *(float4*)&Bs[bk][bc] = *(const float4*)(Bp + (size_t)(kk0 + bk) * CC + bc);
        }
        __syncthreads();

#pragma unroll
        for (int kk = 0; kk < BK; kk++) {
            float a[8], b[8];
            *(float4*)&a[0] = *(const float4*)&As[kk][(ty << 2)];
            *(float4*)&a[4] = *(const float4*)&As[kk][32 + (ty << 2)];
            *(float4*)&b[0] = *(const float4*)&Bs[kk][(tx << 2)];
            *(float4*)&b[4] = *(const float4*)&Bs[kk][128 + (tx << 2)];
#pragma unroll
            for (int i = 0; i < 8; i++)
#pragma unroll
                for (int j = 0; j < 8; j++)
                    acc[i][j] = fmaf(a[i], b[j], acc[i][j]);
        }
        __syncthreads();
    }

    float badd[8];
    {
        float4 a1 = make_float4(0.f, 0.f, 0.f, 0.f), a2 = make_float4(0.f, 0.f, 0.f, 0.f);
        if (bias1) {
            a1 = *(const float4*)(bias1 + (tx << 2));
            a2 = *(const float4*)(bias1 + 128 + (tx << 2));
        }
        if (bias2) {
            const float4 c1 = *(const float4*)(bias2 + (tx << 2));
            const float4 c2 = *(const float4*)(bias2 + 128 + (tx << 2));
            a1.x += c1.x; a1.y += c1.y; a1.z += c1.z; a1.w += c1.w;
            a2.x += c2.x; a2.y += c2.y; a2.z += c2.z; a2.w += c2.w;
        }
        badd[0] = a1.x; badd[1] = a1.y; badd[2] = a1.z; badd[3] = a1.w;
        badd[4] = a2.x; badd[5] = a2.y; badd[6] = a2.z; badd[7] = a2.w;
    }

#pragma unroll
    for (int i = 0; i < 8; i++) {
        const int rf = (i < 4) ? ((ty << 2) + i) : (32 + (ty << 2) + i - 4);
        const int row = m0 + rf;
        if (row < M) {
            float v[8];
#pragma unroll
            for (int j = 0; j < 8; j++) {
                float t = acc[i][j] + badd[j];
                if (SIG) t = 1.0f / (1.0f + __expf(-t));
                v[j] = t;
            }
            *(float4*)(Cout + (size_t)row * CC + (tx << 2))       = make_float4(v[0], v[1], v[2], v[3]);
            *(float4*)(Cout + (size_t)row * CC + 128 + (tx << 2)) = make_float4(v[4], v[5], v[6], v[7]);
        }
    }
}

// ---------------------------------------------------------------------------
// CSR build: histogram -> single-block exclusive scan -> fill (counting sort)
// ---------------------------------------------------------------------------
__global__ __launch_bounds__(256)
void hist_kernel(const int* __restrict__ dst, int* __restrict__ cnt)
{
    const int e = blockIdx.x * 256 + threadIdx.x;
    if (e < EE) atomicAdd(&cnt[dst[e]], 1);
}

__device__ __forceinline__ int wave_incl_scan(int v, int lane)
{
#pragma unroll
    for (int off = 1; off < 64; off <<= 1) {
        int t = __shfl_up(v, off, 64);
        if (lane >= off) v += t;
    }
    return v;
}

// single block, 1024 threads, sequential 1024-wide chunks
__global__ __launch_bounds__(1024)
void exscan_kernel(const int* __restrict__ cnt, int* __restrict__ rowptr, int n)
{
    __shared__ int wsum[16];
    __shared__ int wpre[16];
    __shared__ int chunk_total;
    __shared__ int running;
    const int tid  = threadIdx.x;
    const int lane = tid & 63;
    const int wid  = tid >> 6;
    if (tid == 0) running = 0;
    __syncthreads();

    for (int base = 0; base < n; base += 1024) {
        const int i = base + tid;
        const int v = (i < n) ? cnt[i] : 0;
        const int incl = wave_incl_scan(v, lane);
        if (lane == 63) wsum[wid] = incl;
        __syncthreads();
        if (wid == 0) {
            const int s  = (lane < 16) ? wsum[lane] : 0;
            const int si = wave_incl_scan(s, lane);
            if (lane < 16) wpre[lane] = si - s;       // exclusive wave prefix
            if (lane == 15) chunk_total = si;
        }
        __syncthreads();
        if (i < n) rowptr[i] = running + wpre[wid] + incl - v;
        __syncthreads();
        if (tid == 0) running += chunk_total;
        __syncthreads();
    }
    if (tid == 0) rowptr[n] = running;
}

__global__ __launch_bounds__(256)
void fillcsr_kernel(const int* __restrict__ src, const int* __restrict__ dst,
                    const int* __restrict__ rowptr, int* __restrict__ fill,
                    int* __restrict__ ssrc)
{
    const int e = blockIdx.x * 256 + threadIdx.x;
    if (e < EE) {
        const int d = dst[e];
        const int pos = rowptr[d] + atomicAdd(&fill[d], 1);
        ssrc[pos] = src[e];
    }
}

// ---------------------------------------------------------------------------
// Gather-side mean aggregation: one block per dst node, one thread per channel.
// ---------------------------------------------------------------------------
__global__ __launch_bounds__(256)
void agg_kernel(const float* __restrict__ feat, const int* __restrict__ rowptr,
                const int* __restrict__ ssrc, float* __restrict__ out)
{
    const int node = blockIdx.x;
    const int tid = threadIdx.x;
    const int beg = rowptr[node], end = rowptr[node + 1];
    float acc = 0.0f;
    int i = beg;
    for (; i + 4 <= end; i += 4) {
        const int s0 = ssrc[i], s1 = ssrc[i + 1], s2 = ssrc[i + 2], s3 = ssrc[i + 3];
        float a0 = feat[(size_t)s0 * CC + tid];
        float a1 = feat[(size_t)s1 * CC + tid];
        float a2 = feat[(size_t)s2 * CC + tid];
        float a3 = feat[(size_t)s3 * CC + tid];
        acc += (a0 + a1) + (a2 + a3);
    }
    for (; i < end; ++i) acc += feat[(size_t)ssrc[i] * CC + tid];
    const float inv = 1.0f / fmaxf((float)(end - beg), 1.0f);
    out[(size_t)node * CC + tid] = acc * inv;
}

// ---------------------------------------------------------------------------
extern "C" void kernel_launch(void* const* d_in, const int* in_sizes, int n_in,
                              void* d_out, int out_size, void* d_ws, size_t ws_size,
                              hipStream_t stream)
{
    const float* x_A    = (const float*)d_in[0];
    const float* x_B    = (const float*)d_in[1];
    const int*   e_ab   = (const int*)d_in[4];
    const int*   e_ba   = (const int*)d_in[5];
    const float* lin_A  = (const float*)d_in[6];
    const float* lin_B  = (const float*)d_in[7];
    const float* bias_A = (const float*)d_in[8];
    const float* bias_B = (const float*)d_in[9];
    const float* Wl_ab0 = (const float*)d_in[10]; const float* bl_ab0 = (const float*)d_in[11]; const float* Wr_ab0 = (const float*)d_in[12];
    const float* Wl_ba0 = (const float*)d_in[13]; const float* bl_ba0 = (const float*)d_in[14]; const float* Wr_ba0 = (const float*)d_in[15];
    const float* Wl_ab1 = (const float*)d_in[16]; const float* bl_ab1 = (const float*)d_in[17]; const float* Wr_ab1 = (const float*)d_in[18];
    const float* Wl_ba1 = (const float*)d_in[19]; const float* bl_ba1 = (const float*)d_in[20]; const float* Wr_ba1 = (const float*)d_in[21];

    float* gA = (float*)d_out;
    float* gB = gA + (size_t)NN * CC;

    // workspace: bufA | bufB | agg | ssrc_ba | ssrc_ab | rowptr_ba | rowptr_ab | fill
    float* bufA = (float*)d_ws;
    float* bufB = bufA + (size_t)NN * CC;
    float* agg  = bufB + (size_t)NN * CC;
    int* ssrc_ba   = (int*)(agg + (size_t)NN * CC);
    int* ssrc_ab   = ssrc_ba + EE;
    int* rowptr_ba = ssrc_ab + EE;
    int* rowptr_ab = rowptr_ba + (NN + 1);
    int* fill      = rowptr_ab + (NN + 1);

    const int* src_ab = e_ab;  const int* dst_ab = e_ab + EE;
    const int* src_ba = e_ba;  const int* dst_ba = e_ba + EE;

    const int gM  = (NN + 63) / 64;
    const int gE  = (EE + 255) / 256;
    const int gN  = NN;

    // ---- CSR build for ba (dst = A nodes) ----
    hipMemsetAsync(fill, 0, NN * sizeof(int), stream);
    hist_kernel<<<gE, 256, 0, stream>>>(dst_ba, fill);
    exscan_kernel<<<1, 1024, 0, stream>>>(fill, rowptr_ba, NN);
    hipMemsetAsync(fill, 0, NN * sizeof(int), stream);
    fillcsr_kernel<<<gE, 256, 0, stream>>>(src_ba, dst_ba, rowptr_ba, fill, ssrc_ba);

    // ---- CSR build for ab (dst = B nodes) ----
    hipMemsetAsync(fill, 0, NN * sizeof(int), stream);
    hist_kernel<<<gE, 256, 0, stream>>>(dst_ab, fill);
    exscan_kernel<<<1, 1024, 0, stream>>>(fill, rowptr_ab, NN);
    hipMemsetAsync(fill, 0, NN * sizeof(int), stream);
    fillcsr_kernel<<<gE, 256, 0, stream>>>(src_ab, dst_ab, rowptr_ab, fill, ssrc_ab);

    // ---- input projections ----
    gemm_kernel<0, FF, false><<<gM, 256, 0, stream>>>(nullptr, x_A, nullptr, lin_A, nullptr, nullptr, bufA, NN);
    gemm_kernel<0, FF, false><<<gM, 256, 0, stream>>>(nullptr, x_B, nullptr, lin_B, nullptr, nullptr, bufB, NN);

    // ---- layer 0 ----
    agg_kernel<<<gN, 256, 0, stream>>>(bufB, rowptr_ba, ssrc_ba, agg);   // mean B->A
    gemm_kernel<CC, CC, false><<<gM, 256, 0, stream>>>(agg, bufA, Wl_ba0, Wr_ba0, bl_ba0, nullptr, gA, NN);
    agg_kernel<<<gN, 256, 0, stream>>>(bufA, rowptr_ab, ssrc_ab, agg);   // mean A->B
    gemm_kernel<CC, CC, false><<<gM, 256, 0, stream>>>(agg, bufB, Wl_ab0, Wr_ab0, bl_ab0, nullptr, gB, NN);

    // ---- layer 1: both aggregations first (gA/gB intact), then in-place GEMMs ----
    agg_kernel<<<gN, 256, 0, stream>>>(gB, rowptr_ba, ssrc_ba, agg);     // mean B->A
    agg_kernel<<<gN, 256, 0, stream>>>(gA, rowptr_ab, ssrc_ab, bufA);    // mean A->B (bufA dead)
    gemm_kernel<CC, CC, true><<<gM, 256, 0, stream>>>(agg,  gA, Wl_ba1, Wr_ba1, bl_ba1, bias_A, gA, NN);
    gemm_kernel<CC, CC, true><<<gM, 256, 0, stream>>>(bufA, gB, Wl_ab1, Wr_ab1, bl_ab1, bias_B, gB, NN);
}

// Round 3
// 1593.577 us; speedup vs baseline: 14.6046x; 2.0018x over previous
//
#include <hip/hip_runtime.h>
#include <math.h>

#define NN 100000
#define EE 1600000

typedef short s16x8 __attribute__((ext_vector_type(8)));
typedef float f32x4 __attribute__((ext_vector_type(4)));

union FragU { uint4 u; s16x8 s; };

__device__ __forceinline__ unsigned short f2bf(float x) {
    unsigned int u = __float_as_uint(x);
    u = (u + 0x7fff + ((u >> 16) & 1)) >> 16;   // round-to-nearest-even
    return (unsigned short)u;
}
__device__ __forceinline__ float bf2f(unsigned short b) {
    return __uint_as_float(((unsigned int)b) << 16);
}

__device__ __forceinline__ void gload16(const unsigned short* g, unsigned short* l) {
    __builtin_amdgcn_global_load_lds(
        (const __attribute__((address_space(1))) unsigned int*)g,
        (__attribute__((address_space(3))) unsigned int*)l, 16, 0, 0);
}

// ---------------------------------------------------------------------------
// bf16 MFMA GEMM (m97 structure): BM=BN=128, BK=32, 256 thr = 4 waves (2x2),
// each wave a 64x64 tile = 4x4 MFMA 16x16x32. A = [A1 | A2] along K (row-major
// bf16, strides K1/K2). BT = B transposed [256][K1+K2] bf16. Staging via
// global_load_lds(16B), LDS unpadded in lane order.
// MODE 0: bf16 out (+optional bias bl). MODE 1: fp32 sigmoid(acc+bl+b2) out.
// ---------------------------------------------------------------------------
template<int K1, int K2, int MODE>
__global__ __launch_bounds__(256)
void gemm_mfma(const unsigned short* __restrict__ A1,
               const unsigned short* __restrict__ A2,
               const unsigned short* __restrict__ BT,
               const float* __restrict__ bl, const float* __restrict__ b2,
               void* __restrict__ Cout, int M)
{
    constexpr int KT = K1 + K2;
    __shared__ __align__(16) unsigned short As[128 * 32];
    __shared__ __align__(16) unsigned short Bs[128 * 32];

    const int tid  = threadIdx.x;
    const int w    = tid >> 6, lane = tid & 63;
    const int l15  = lane & 15, g = lane >> 4;
    const int m0   = blockIdx.x * 128;
    const int n0   = blockIdx.y * 128;
    const int wm   = (w >> 1) * 64, wn = (w & 1) * 64;

    f32x4 acc[4][4];
#pragma unroll
    for (int i = 0; i < 4; i++)
#pragma unroll
        for (int j = 0; j < 4; j++) { acc[i][j][0]=0.f; acc[i][j][1]=0.f; acc[i][j][2]=0.f; acc[i][j][3]=0.f; }

    for (int k0 = 0; k0 < KT; k0 += 32) {
        const unsigned short* Ap; int astr, kloc;
        if (K1 > 0 && k0 < K1) { Ap = A1; astr = K1; kloc = k0; }
        else                   { Ap = A2; astr = K2; kloc = k0 - K1; }

#pragma unroll
        for (int c = 0; c < 2; c++) {
            const int chunk = ((w * 2 + c) << 6) + lane;   // 16B chunk id in tile
            const int row = chunk >> 2, kc = chunk & 3;
            int rg = m0 + row; if (rg > M - 1) rg = M - 1;
            // LDS dest: wave-uniform base; HW scatters lane*16B
            gload16(Ap + (size_t)rg * astr + kloc + kc * 8, As + (w * 2 + c) * 512);
            gload16(BT + (size_t)(n0 + row) * KT + k0 + kc * 8, Bs + (w * 2 + c) * 512);
        }
        __syncthreads();   // drains vmcnt before LDS reads

        FragU a[4], b[4];
#pragma unroll
        for (int i = 0; i < 4; i++) {
            a[i].u = *(const uint4*)(As + (wm + i * 16 + l15) * 32 + g * 8);
            b[i].u = *(const uint4*)(Bs + (wn + i * 16 + l15) * 32 + g * 8);
        }
#pragma unroll
        for (int i = 0; i < 4; i++)
#pragma unroll
            for (int j = 0; j < 4; j++)
                acc[i][j] = __builtin_amdgcn_mfma_f32_16x16x32_bf16(a[i].s, b[j].s, acc[i][j], 0, 0, 0);
        __syncthreads();
    }

    // epilogue: C/D layout col=lane&15, row=(lane>>4)*4+reg (m89-verified)
    float badd[4];
#pragma unroll
    for (int j = 0; j < 4; j++) {
        const int col = n0 + wn + j * 16 + l15;
        badd[j] = bl ? bl[col] : 0.0f;
        if (MODE == 1) badd[j] += b2[col];
    }
#pragma unroll
    for (int i = 0; i < 4; i++) {
#pragma unroll
        for (int r = 0; r < 4; r++) {
            const int rowg = m0 + wm + i * 16 + g * 4 + r;
            if (rowg < M) {
#pragma unroll
                for (int j = 0; j < 4; j++) {
                    const int col = n0 + wn + j * 16 + l15;
                    float t = acc[i][j][r] + badd[j];
                    if (MODE == 1) {
                        t = 1.0f / (1.0f + __expf(-t));
                        ((float*)Cout)[(size_t)rowg * 256 + col] = t;
                    } else {
                        ((unsigned short*)Cout)[(size_t)rowg * 256 + col] = f2bf(t);
                    }
                }
            }
        }
    }
}

// ---------------------------------------------------------------------------
// CSR build (R2-proven): histogram -> single-block scan -> fill
// ---------------------------------------------------------------------------
__global__ __launch_bounds__(256)
void hist_kernel(const int* __restrict__ dst, int* __restrict__ cnt)
{
    const int e = blockIdx.x * 256 + threadIdx.x;
    if (e < EE) atomicAdd(&cnt[dst[e]], 1);
}

__device__ __forceinline__ int wave_incl_scan(int v, int lane)
{
#pragma unroll
    for (int off = 1; off < 64; off <<= 1) {
        int t = __shfl_up(v, off, 64);
        if (lane >= off) v += t;
    }
    return v;
}

__global__ __launch_bounds__(1024)
void exscan_kernel(const int* __restrict__ cnt, int* __restrict__ rowptr, int n)
{
    __shared__ int wsum[16];
    __shared__ int wpre[16];
    __shared__ int chunk_total;
    __shared__ int running;
    const int tid  = threadIdx.x;
    const int lane = tid & 63;
    const int wid  = tid >> 6;
    if (tid == 0) running = 0;
    __syncthreads();

    for (int base = 0; base < n; base += 1024) {
        const int i = base + tid;
        const int v = (i < n) ? cnt[i] : 0;
        const int incl = wave_incl_scan(v, lane);
        if (lane == 63) wsum[wid] = incl;
        __syncthreads();
        if (wid == 0) {
            const int s  = (lane < 16) ? wsum[lane] : 0;
            const int si = wave_incl_scan(s, lane);
            if (lane < 16) wpre[lane] = si - s;
            if (lane == 15) chunk_total = si;
        }
        __syncthreads();
        if (i < n) rowptr[i] = running + wpre[wid] + incl - v;
        __syncthreads();
        if (tid == 0) running += chunk_total;
        __syncthreads();
    }
    if (tid == 0) rowptr[n] = running;
}

__global__ __launch_bounds__(256)
void fillcsr_kernel(const int* __restrict__ src, const int* __restrict__ dst,
                    const int* __restrict__ rowptr, int* __restrict__ fill,
                    int* __restrict__ ssrc)
{
    const int e = blockIdx.x * 256 + threadIdx.x;
    if (e < EE) {
        const int d = dst[e];
        const int pos = rowptr[d] + atomicAdd(&fill[d], 1);
        ssrc[pos] = src[e];
    }
}

// ---------------------------------------------------------------------------
// bf16 gather-mean: one block (128 thr) per dst node, 2 channels/thread.
// ---------------------------------------------------------------------------
__global__ __launch_bounds__(128)
void agg_bf(const unsigned short* __restrict__ feat, const int* __restrict__ rowptr,
            const int* __restrict__ ssrc, unsigned short* __restrict__ out)
{
    const int node = blockIdx.x;
    const int t = threadIdx.x;              // channels 2t, 2t+1
    const int beg = rowptr[node], end = rowptr[node + 1];
    float a0 = 0.f, a1 = 0.f;
    int i = beg;
    for (; i + 4 <= end; i += 4) {
        const int s0 = ssrc[i], s1 = ssrc[i+1], s2 = ssrc[i+2], s3 = ssrc[i+3];
        const unsigned int v0 = *(const unsigned int*)(feat + (size_t)s0 * 256 + t * 2);
        const unsigned int v1 = *(const unsigned int*)(feat + (size_t)s1 * 256 + t * 2);
        const unsigned int v2 = *(const unsigned int*)(feat + (size_t)s2 * 256 + t * 2);
        const unsigned int v3 = *(const unsigned int*)(feat + (size_t)s3 * 256 + t * 2);
        a0 += bf2f((unsigned short)v0) + bf2f((unsigned short)v1)
            + bf2f((unsigned short)v2) + bf2f((unsigned short)v3);
        a1 += bf2f((unsigned short)(v0 >> 16)) + bf2f((unsigned short)(v1 >> 16))
            + bf2f((unsigned short)(v2 >> 16)) + bf2f((unsigned short)(v3 >> 16));
    }
    for (; i < end; ++i) {
        const unsigned int v = *(const unsigned int*)(feat + (size_t)ssrc[i] * 256 + t * 2);
        a0 += bf2f((unsigned short)v);
        a1 += bf2f((unsigned short)(v >> 16));
    }
    const float inv = 1.0f / fmaxf((float)(end - beg), 1.0f);
    const unsigned int packed = (unsigned int)f2bf(a0 * inv) | ((unsigned int)f2bf(a1 * inv) << 16);
    *(unsigned int*)(out + (size_t)node * 256 + t * 2) = packed;
}

// ---------------------------------------------------------------------------
// converts
// ---------------------------------------------------------------------------
__global__ __launch_bounds__(256)
void f2bf4_kernel(const float* __restrict__ in, unsigned short* __restrict__ out, int n4)
{
    const int i = blockIdx.x * 256 + threadIdx.x;
    if (i < n4) {
        const float4 v = ((const float4*)in)[i];
        ushort4 o;
        o.x = f2bf(v.x); o.y = f2bf(v.y); o.z = f2bf(v.z); o.w = f2bf(v.w);
        ((ushort4*)out)[i] = o;
    }
}

// W [K][256] fp32 -> WT [256][KT] bf16 at column offset koff
__global__ __launch_bounds__(256)
void wt_kernel(const float* __restrict__ W, unsigned short* __restrict__ WT,
               int K, int KT, int koff)
{
    const int idx = blockIdx.x * 256 + threadIdx.x;
    if (idx < K * 256) {
        const int k = idx >> 8, n = idx & 255;
        WT[(size_t)n * KT + koff + k] = f2bf(W[(size_t)k * 256 + n]);
    }
}

// ---------------------------------------------------------------------------
extern "C" void kernel_launch(void* const* d_in, const int* in_sizes, int n_in,
                              void* d_out, int out_size, void* d_ws, size_t ws_size,
                              hipStream_t stream)
{
    const float* x_A    = (const float*)d_in[0];
    const float* x_B    = (const float*)d_in[1];
    const int*   e_ab   = (const int*)d_in[4];
    const int*   e_ba   = (const int*)d_in[5];
    const float* lin_A  = (const float*)d_in[6];
    const float* lin_B  = (const float*)d_in[7];
    const float* bias_A = (const float*)d_in[8];
    const float* bias_B = (const float*)d_in[9];
    const float* Wl_ab0 = (const float*)d_in[10]; const float* bl_ab0 = (const float*)d_in[11]; const float* Wr_ab0 = (const float*)d_in[12];
    const float* Wl_ba0 = (const float*)d_in[13]; const float* bl_ba0 = (const float*)d_in[14]; const float* Wr_ba0 = (const float*)d_in[15];
    const float* Wl_ab1 = (const float*)d_in[16]; const float* bl_ab1 = (const float*)d_in[17]; const float* Wr_ab1 = (const float*)d_in[18];
    const float* Wl_ba1 = (const float*)d_in[19]; const float* bl_ba1 = (const float*)d_in[20]; const float* Wr_ba1 = (const float*)d_in[21];

    float* gA = (float*)d_out;
    float* gB = gA + (size_t)NN * 256;

    // ---- workspace carve (ushort units) ----
    const size_t HALF = (size_t)NN * 128;           // 12.8M
    const size_t FULL = (size_t)NN * 256;           // 25.6M
    unsigned short* xb    = (unsigned short*)d_ws;  // xbA|xbB; later l0A
    unsigned short* xbA   = xb;
    unsigned short* xbB   = xb + HALF;
    unsigned short* l0A   = xb;                     // reuse after proj GEMMs
    unsigned short* projA = xb + FULL;              // later l0B
    unsigned short* l0B   = projA;
    unsigned short* projB = projA + FULL;
    unsigned short* aggb  = projB + FULL;
    unsigned short* linAT = aggb + FULL;            // [256][128]
    unsigned short* linBT = linAT + 256 * 128;
    unsigned short* WTba0 = linBT + 256 * 128;      // [256][512] each
    unsigned short* WTab0 = WTba0 + 256 * 512;
    unsigned short* WTba1 = WTab0 + 256 * 512;
    unsigned short* WTab1 = WTba1 + 256 * 512;
    int* ssrc_ba   = (int*)(WTab1 + 256 * 512);
    int* ssrc_ab   = ssrc_ba + EE;
    int* rowptr_ba = ssrc_ab + EE;
    int* rowptr_ab = rowptr_ba + (NN + 1);
    int* fill      = rowptr_ab + (NN + 1);

    const int* src_ab = e_ab;  const int* dst_ab = e_ab + EE;
    const int* src_ba = e_ba;  const int* dst_ba = e_ba + EE;

    const int gE = (EE + 255) / 256;
    const dim3 gg((NN + 127) / 128, 2);             // 782 x 2

    // ---- CSR build ----
    hipMemsetAsync(fill, 0, NN * sizeof(int), stream);
    hist_kernel<<<gE, 256, 0, stream>>>(dst_ba, fill);
    exscan_kernel<<<1, 1024, 0, stream>>>(fill, rowptr_ba, NN);
    hipMemsetAsync(fill, 0, NN * sizeof(int), stream);
    fillcsr_kernel<<<gE, 256, 0, stream>>>(src_ba, dst_ba, rowptr_ba, fill, ssrc_ba);

    hipMemsetAsync(fill, 0, NN * sizeof(int), stream);
    hist_kernel<<<gE, 256, 0, stream>>>(dst_ab, fill);
    exscan_kernel<<<1, 1024, 0, stream>>>(fill, rowptr_ab, NN);
    hipMemsetAsync(fill, 0, NN * sizeof(int), stream);
    fillcsr_kernel<<<gE, 256, 0, stream>>>(src_ab, dst_ab, rowptr_ab, fill, ssrc_ab);

    // ---- convert inputs & weights to bf16 (weights transposed) ----
    f2bf4_kernel<<<(int)(HALF / 4 + 255) / 256, 256, 0, stream>>>(x_A, xbA, (int)(HALF / 4));
    f2bf4_kernel<<<(int)(HALF / 4 + 255) / 256, 256, 0, stream>>>(x_B, xbB, (int)(HALF / 4));
    wt_kernel<<<128, 256, 0, stream>>>(lin_A, linAT, 128, 128, 0);
    wt_kernel<<<128, 256, 0, stream>>>(lin_B, linBT, 128, 128, 0);
    wt_kernel<<<256, 256, 0, stream>>>(Wl_ba0, WTba0, 256, 512, 0);
    wt_kernel<<<256, 256, 0, stream>>>(Wr_ba0, WTba0, 256, 512, 256);
    wt_kernel<<<256, 256, 0, stream>>>(Wl_ab0, WTab0, 256, 512, 0);
    wt_kernel<<<256, 256, 0, stream>>>(Wr_ab0, WTab0, 256, 512, 256);
    wt_kernel<<<256, 256, 0, stream>>>(Wl_ba1, WTba1, 256, 512, 0);
    wt_kernel<<<256, 256, 0, stream>>>(Wr_ba1, WTba1, 256, 512, 256);
    wt_kernel<<<256, 256, 0, stream>>>(Wl_ab1, WTab1, 256, 512, 0);
    wt_kernel<<<256, 256, 0, stream>>>(Wr_ab1, WTab1, 256, 512, 256);

    // ---- input projections (bf16 out) ----
    gemm_mfma<0, 128, 0><<<gg, 256, 0, stream>>>(nullptr, xbA, linAT, nullptr, nullptr, projA, NN);
    gemm_mfma<0, 128, 0><<<gg, 256, 0, stream>>>(nullptr, xbB, linBT, nullptr, nullptr, projB, NN);

    // ---- layer 0 ----
    agg_bf<<<NN, 128, 0, stream>>>(projB, rowptr_ba, ssrc_ba, aggb);          // mean B->A
    gemm_mfma<256, 256, 0><<<gg, 256, 0, stream>>>(aggb, projA, WTba0, bl_ba0, nullptr, l0A, NN);
    agg_bf<<<NN, 128, 0, stream>>>(projA, rowptr_ab, ssrc_ab, aggb);          // mean A->B (projA last read... by this)
    gemm_mfma<256, 256, 0><<<gg, 256, 0, stream>>>(aggb, projB, WTab0, bl_ab0, nullptr, l0B, NN);

    // ---- layer 1 (final: fp32 + per-type bias + sigmoid into d_out) ----
    agg_bf<<<NN, 128, 0, stream>>>(l0B, rowptr_ba, ssrc_ba, aggb);            // mean B->A
    gemm_mfma<256, 256, 1><<<gg, 256, 0, stream>>>(aggb, l0A, WTba1, bl_ba1, bias_A, gA, NN);
    agg_bf<<<NN, 128, 0, stream>>>(l0A, rowptr_ab, ssrc_ab, aggb);            // mean A->B
    gemm_mfma<256, 256, 1><<<gg, 256, 0, stream>>>(aggb, l0B, WTab1, bl_ab1, bias_B, gB, NN);
}